// Round 5
// baseline (280.638 us; speedup 1.0000x reference)
//
#include <hip/hip_runtime.h>
#include <math.h>

#define BB 4
#define NN 4096
#define KNBR 20
#define BN (BB * NN)
#define HALF 2048          // summed indices per block-half
#define RPW 128            // summed indices per wave (2048/16)

__device__ __forceinline__ float gelu_f(float x) {
    return 0.5f * x * (1.0f + erff(x * 0.70710678118654752440f));
}

// ---------------- K0: per-point precompute: q, k, packed (x,y,z,|p|^2) ----
__global__ void k0_prep(const float* __restrict__ xyz,
                        const float* __restrict__ w_q, const float* __restrict__ g_q, const float* __restrict__ b_q,
                        const float* __restrict__ w_k, const float* __restrict__ g_k, const float* __restrict__ b_k,
                        float* __restrict__ qv, float* __restrict__ kv, float4* __restrict__ pts4) {
    int t = blockIdx.x * blockDim.x + threadIdx.x;
    if (t >= BN) return;
    int b = t / NN, n = t % NN;
    const float* base = xyz + (size_t)b * 3 * NN;
    float x = base[n], y = base[NN + n], z = base[2 * NN + n];
    float sq = x * x + y * y + z * z;
    const float invs = rsqrtf(1.0f + 1e-5f);
    float qr = x * (w_q[0] + w_q[3]) + y * (w_q[1] + w_q[4]) + z * (w_q[2] + w_q[5]);
    float kr = x * (w_k[0] + w_k[3]) + y * (w_k[1] + w_k[4]) + z * (w_k[2] + w_k[5]);
    qv[t] = qr * (g_q[0] * invs) + b_q[0];
    kv[t] = kr * (g_k[0] * invs) + b_k[0];
    pts4[t] = make_float4(x, y, z, sq);
}

// ---------------- P1: kd partials (unroll-8 batched loads) ----------------
__global__ __launch_bounds__(1024, 8)
void p1_kd(const float4* __restrict__ pts4, float* __restrict__ part) {
    int tid = threadIdx.x;
    int wave = __builtin_amdgcn_readfirstlane(tid >> 6);
    int lane = tid & 63;
    int g = blockIdx.x >> 1, half = blockIdx.x & 1;
    int b = g >> 6;
    const float4* p = pts4 + (size_t)b * NN;
    float4 fr = pts4[g * 64 + lane];
    float acc = 0.f;
    int i0 = half * HALF + wave * RPW;
    for (int i = i0; i < i0 + RPW; i += 8) {
        float4 fc[8];
        #pragma unroll
        for (int u = 0; u < 8; ++u) fc[u] = p[i + u];
        #pragma unroll
        for (int u = 0; u < 8; ++u) {
            float dot = fr.x * fc[u].x + fr.y * fc[u].y + fr.z * fc[u].z;
            float d = fmaf(-2.0f, dot, fr.w) + fc[u].w;
            acc += __expf(-50.0f * d);
        }
    }
    __shared__ float s_red[16][64];
    s_red[wave][lane] = acc;
    __syncthreads();
    if (tid < 64) {
        float s = 0.f;
        #pragma unroll
        for (int w = 0; w < 16; ++w) s += s_red[w][tid];
        part[half * BN + g * 64 + tid] = s;
    }
}

// ---------------- K2: reduce kd + per-batch max -> radius; write recB -----
// recB[2n] = {x,y,z,sq}; recB[2n+1] = {k, q, rad, 0}
__global__ void k2_radius(const float* __restrict__ part, const float4* __restrict__ pts4,
                          const float* __restrict__ qv, const float* __restrict__ kv,
                          float* __restrict__ radius, float4* __restrict__ recB) {
    int b = blockIdx.x;
    int t = threadIdx.x;   // 1024
    float kdv[4];
    float mx = -1e30f;
    #pragma unroll
    for (int j = 0; j < 4; ++j) {
        int n = b * NN + j * 1024 + t;
        kdv[j] = part[n] + part[BN + n];
        mx = fmaxf(mx, kdv[j]);
    }
    __shared__ float red[1024];
    red[t] = mx;
    __syncthreads();
    for (int s = 512; s > 0; s >>= 1) {
        if (t < s) red[t] = fmaxf(red[t], red[t + s]);
        __syncthreads();
    }
    float kmax = red[0];
    #pragma unroll
    for (int j = 0; j < 4; ++j) {
        int n = b * NN + j * 1024 + t;
        float rad = 0.1f + 0.1f * (kdv[j] / (kmax + 1e-9f));
        radius[n] = rad;
        recB[2 * n] = pts4[n];
        recB[2 * n + 1] = make_float4(kv[n], qv[n], rad, 0.f);
    }
}

// ---------------- P3: Z partials + k7 neighbor scan ----------------------
__global__ __launch_bounds__(1024, 8)
void p3_Zk7(const float4* __restrict__ recB, const float4* __restrict__ pts4,
            const float* __restrict__ radius, float* __restrict__ part,
            int* __restrict__ idxg) {
    int tid = threadIdx.x;
    int wave = __builtin_amdgcn_readfirstlane(tid >> 6);
    int lane = tid & 63;
    int g = blockIdx.x >> 1, half = blockIdx.x & 1;
    int b = g >> 6;
    const float4* rb = recB + (size_t)b * NN * 2;
    int row = g * 64 + lane;
    float4 fr = recB[2 * row];
    float4 rowa = recB[2 * row + 1];
    float qn = rowa.y, rad = rowa.z;
    float acc = 0.f;
    int i0 = half * HALF + wave * RPW;
    for (int i = i0; i < i0 + RPW; i += 8) {
        float4 fc[8], an[8];
        #pragma unroll
        for (int u = 0; u < 8; ++u) {
            fc[u] = rb[2 * (i + u)];
            an[u] = rb[2 * (i + u) + 1];
        }
        #pragma unroll
        for (int u = 0; u < 8; ++u) {
            float dot = fr.x * fc[u].x + fr.y * fc[u].y + fr.z * fc[u].z;
            float d = fmaf(-2.0f, dot, fr.w) + fc[u].w;
            float e = __expf(qn * an[u].x);
            acc += (d < rad) ? e : 0.f;
        }
    }
    __shared__ float s_red[16][64];
    s_red[wave][lane] = acc;
    __syncthreads();
    if (tid < 64) {
        float s = 0.f;
        #pragma unroll
        for (int w = 0; w < 16; ++w) s += s_red[w][tid];
        part[half * BN + g * 64 + tid] = s;
    }
    // k7: first-20-by-index in-ball neighbors; 2 rows per wave
    int gw = blockIdx.x * 16 + wave;
    for (int rr = 0; rr < 2; ++rr) {
        int row7 = gw * 2 + rr;
        int b7 = row7 / NN;
        const float4* p7 = pts4 + (size_t)b7 * NN;
        float4 f7 = pts4[row7];
        float rad7 = radius[row7];
        int total = 0, firstm = 0;
        bool have = false;
        unsigned long long lmask = (1ULL << lane) - 1ULL;
        for (int i = 0; i < NN / 64 && total < KNBR; ++i) {
            int m = i * 64 + lane;
            float4 fc = p7[m];
            float dot = f7.x * fc.x + f7.y * fc.y + f7.z * fc.z;
            float d = fmaf(-2.0f, dot, f7.w) + fc.w;
            bool inb = !(d > rad7);   // dist <= radius
            unsigned long long mask = __ballot(inb);
            if (!have && mask != 0ULL) {
                int src = __ffsll(mask) - 1;
                firstm = __shfl(m, src);
                have = true;
            }
            int pos = total + (int)__popcll(mask & lmask);
            if (inb && pos < KNBR) idxg[(size_t)row7 * KNBR + pos] = m;
            total += (int)__popcll(mask);
        }
        if (total < KNBR && lane >= total && lane < KNBR)
            idxg[(size_t)row7 * KNBR + lane] = firstm;
    }
}

// ---------------- R3: Z = sum; recC = {pts4},{q, rad, lnZ, 0} -------------
__global__ void r3_Z(const float* __restrict__ part, const float4* __restrict__ pts4,
                     const float* __restrict__ qv, const float* __restrict__ radius,
                     float* __restrict__ Z, float4* __restrict__ recC) {
    int t = blockIdx.x * blockDim.x + threadIdx.x;
    float s = part[t] + part[BN + t];
    Z[t] = s;
    recC[2 * t] = pts4[t];
    recC[2 * t + 1] = make_float4(qv[t], radius[t], __logf(s), 0.f);
}

// ---------------- P4: colsum partials (col pass) --------------------------
__global__ __launch_bounds__(1024, 8)
void p4_colsum(const float4* __restrict__ recC, const float4* __restrict__ recB,
               float* __restrict__ part) {
    int tid = threadIdx.x;
    int wave = __builtin_amdgcn_readfirstlane(tid >> 6);
    int lane = tid & 63;
    int g = blockIdx.x >> 1, half = blockIdx.x & 1;
    int b = g >> 6;
    const float4* rc = recC + (size_t)b * NN * 2;
    int col = g * 64 + lane;
    float4 fcc = recB[2 * col];
    float km = recB[2 * col + 1].x;
    float acc = 0.f;
    int i0 = half * HALF + wave * RPW;
    for (int i = i0; i < i0 + RPW; i += 8) {
        float4 fr[8], an[8];
        #pragma unroll
        for (int u = 0; u < 8; ++u) {
            fr[u] = rc[2 * (i + u)];
            an[u] = rc[2 * (i + u) + 1];
        }
        #pragma unroll
        for (int u = 0; u < 8; ++u) {
            float dot = fr[u].x * fcc.x + fr[u].y * fcc.y + fr[u].z * fcc.z;
            float d = fmaf(-2.0f, dot, fr[u].w) + fcc.w;
            float e = __expf(an[u].x * km - an[u].z);
            acc += (d < an[u].y) ? e : 0.f;
        }
    }
    __shared__ float s_red[16][64];
    s_red[wave][lane] = acc;
    __syncthreads();
    if (tid < 64) {
        float s = 0.f;
        #pragma unroll
        for (int w = 0; w < 16; ++w) s += s_red[w][tid];
        part[half * BN + g * 64 + tid] = s;
    }
}

// ---------------- R4: colsum; recD = {pts4},{k, ln colsum, 0, 0} ----------
__global__ void r4_colsum(const float* __restrict__ part, const float4* __restrict__ pts4,
                          const float* __restrict__ kv, float* __restrict__ colsum,
                          float4* __restrict__ recD) {
    int t = blockIdx.x * blockDim.x + threadIdx.x;
    float s = fmaxf(part[t] + part[BN + t], 1e-12f);
    colsum[t] = s;
    recD[2 * t] = pts4[t];
    recD[2 * t + 1] = make_float4(kv[t], __logf(s), 0.f, 0.f);
}

// ---------------- P5: rs partials (row pass) ------------------------------
__global__ __launch_bounds__(1024, 8)
void p5_rs(const float4* __restrict__ recD, const float4* __restrict__ recB,
           float* __restrict__ part) {
    int tid = threadIdx.x;
    int wave = __builtin_amdgcn_readfirstlane(tid >> 6);
    int lane = tid & 63;
    int g = blockIdx.x >> 1, half = blockIdx.x & 1;
    int b = g >> 6;
    const float4* rd = recD + (size_t)b * NN * 2;
    int row = g * 64 + lane;
    float4 fr = recB[2 * row];
    float4 rowa = recB[2 * row + 1];
    float qn = rowa.y, rad = rowa.z;
    float acc = 0.f;
    int i0 = half * HALF + wave * RPW;
    for (int i = i0; i < i0 + RPW; i += 8) {
        float4 fc[8], an[8];
        #pragma unroll
        for (int u = 0; u < 8; ++u) {
            fc[u] = rd[2 * (i + u)];
            an[u] = rd[2 * (i + u) + 1];
        }
        #pragma unroll
        for (int u = 0; u < 8; ++u) {
            float dot = fr.x * fc[u].x + fr.y * fc[u].y + fr.z * fc[u].z;
            float d = fmaf(-2.0f, dot, fr.w) + fc[u].w;
            float e = __expf(qn * an[u].x - an[u].y);
            acc += (d < rad) ? e : 0.f;
        }
    }
    __shared__ float s_red[16][64];
    s_red[wave][lane] = acc;
    __syncthreads();
    if (tid < 64) {
        float s = 0.f;
        #pragma unroll
        for (int w = 0; w < 16; ++w) s += s_red[w][tid];
        part[half * BN + g * 64 + tid] = s;
    }
}

// ---------------- R5: rs; recE = {pts4},{q, rad, lnZ + ln rs, 0} ----------
__global__ void r5_rs(const float* __restrict__ part, const float* __restrict__ Z,
                      const float4* __restrict__ recC, const float4* __restrict__ pts4,
                      float4* __restrict__ recE) {
    int t = blockIdx.x * blockDim.x + threadIdx.x;
    float s = part[t] + part[BN + t];
    float rs = fmaxf(s / Z[t], 1e-12f);
    float4 a = recC[2 * t + 1];          // {q, rad, lnZ, 0}
    recE[2 * t] = pts4[t];
    recE[2 * t + 1] = make_float4(a.x, a.y, a.z + __logf(rs), 0.f);
}

// ---------------- P6: smoothed partials (col pass, 3 accumulators) --------
__global__ __launch_bounds__(1024, 8)
void p6_smooth(const float4* __restrict__ recE, const float4* __restrict__ recB,
               float* __restrict__ partx, float* __restrict__ party,
               float* __restrict__ partz) {
    int tid = threadIdx.x;
    int wave = __builtin_amdgcn_readfirstlane(tid >> 6);
    int lane = tid & 63;
    int g = blockIdx.x >> 1, half = blockIdx.x & 1;
    int b = g >> 6;
    const float4* re = recE + (size_t)b * NN * 2;
    int col = g * 64 + lane;
    float4 fcc = recB[2 * col];
    float km = recB[2 * col + 1].x;
    float ax = 0.f, ay = 0.f, az = 0.f;
    int i0 = half * HALF + wave * RPW;
    for (int i = i0; i < i0 + RPW; i += 8) {
        float4 fr[8], an[8];
        #pragma unroll
        for (int u = 0; u < 8; ++u) {
            fr[u] = re[2 * (i + u)];
            an[u] = re[2 * (i + u) + 1];
        }
        #pragma unroll
        for (int u = 0; u < 8; ++u) {
            float dot = fr[u].x * fcc.x + fr[u].y * fcc.y + fr[u].z * fcc.z;
            float d = fmaf(-2.0f, dot, fr[u].w) + fcc.w;
            float w = __expf(an[u].x * km - an[u].z);
            w = (d < an[u].y) ? w : 0.f;
            ax += fr[u].x * w;
            ay += fr[u].y * w;
            az += fr[u].z * w;
        }
    }
    __shared__ float s_rx[16][64];
    __shared__ float s_ry[16][64];
    __shared__ float s_rz[16][64];
    s_rx[wave][lane] = ax;
    s_ry[wave][lane] = ay;
    s_rz[wave][lane] = az;
    __syncthreads();
    if (tid < 64) {
        float sx = 0.f, sy = 0.f, sz = 0.f;
        #pragma unroll
        for (int w = 0; w < 16; ++w) {
            sx += s_rx[w][tid];
            sy += s_ry[w][tid];
            sz += s_rz[w][tid];
        }
        int o = half * BN + g * 64 + tid;
        partx[o] = sx;
        party[o] = sy;
        partz[o] = sz;
    }
}

// ---------------- K8: fused epilogue (+ smoothed reduce), 8 thr/point -----
__global__ void k8_final(const float* __restrict__ xyz,
                         const float* __restrict__ partx, const float* __restrict__ party,
                         const float* __restrict__ partz, const float* __restrict__ colsum,
                         const int* __restrict__ idxg,
                         const float* __restrict__ w_v, const float* __restrict__ g_v, const float* __restrict__ b_v,
                         const float* __restrict__ w_pe, const float* __restrict__ b_pe,
                         const float* __restrict__ g_pe, const float* __restrict__ bb_pe,
                         const float* __restrict__ w_m1, const float* __restrict__ g_m1, const float* __restrict__ b_m1,
                         const float* __restrict__ w_m2, const float* __restrict__ g_m2, const float* __restrict__ b_m2,
                         const float* __restrict__ w_out, const float* __restrict__ g_out, const float* __restrict__ b_out,
                         float* __restrict__ out) {
    __shared__ float s_pf8[32][9];
    __shared__ float s_pf16[32][17];
    __shared__ float s_g64[32][65];
    int tid = threadIdx.x;
    int ptL = tid >> 3, o = tid & 7;
    int p = blockIdx.x * 32 + ptL;
    int b = p / NN, n = p % NN;
    const float* xb = xyz + (size_t)b * 3 * NN;
    float x = xb[n], y = xb[NN + n], z = xb[2 * NN + n];
    const float invs = rsqrtf(1.0f + 1e-5f);

    // phase A: PE 9->8, gelu(bn), max over K; thread = channel o
    float w0 = w_pe[o * 9 + 0], w1 = w_pe[o * 9 + 1], w2 = w_pe[o * 9 + 2];
    float w3 = w_pe[o * 9 + 3], w4 = w_pe[o * 9 + 4], w5 = w_pe[o * 9 + 5];
    float w6 = w_pe[o * 9 + 6], w7 = w_pe[o * 9 + 7], w8 = w_pe[o * 9 + 8];
    float bp = b_pe[o], gp = g_pe[o] * invs, bbp = bb_pe[o];
    float mx = -1e30f;
    for (int kk = 0; kk < KNBR; ++kk) {
        int j = idxg[(size_t)p * KNBR + kk];
        float gx = xb[j], gy = xb[NN + j], gz = xb[2 * NN + j];
        float dx = gx - x, dy = gy - y, dz = gz - z;
        float s = w0 * x + w1 * y + w2 * z + w3 * gx + w4 * gy + w5 * gz
                + w6 * dx + w7 * dy + w8 * dz + bp;
        s = gelu_f(s * gp + bbp);
        mx = fmaxf(mx, s);
    }
    s_pf8[ptL][o] = mx;
    __syncthreads();

    // phase B: m1 8->16, outputs o and o+8
    #pragma unroll
    for (int rr = 0; rr < 2; ++rr) {
        int r = o + rr * 8;
        const float* w = w_m1 + r * 8;
        float s = 0.f;
        #pragma unroll
        for (int c = 0; c < 8; ++c) s += w[c] * s_pf8[ptL][c];
        s_pf16[ptL][r] = gelu_f(s * (g_m1[r] * invs) + b_m1[r]);
    }
    __syncthreads();

    // phase C: m2 16->64 + value conv, gelu(v+pos); channels o*8..o*8+7
    float inv = 1.0f / colsum[p];
    float vx = (partx[p] + partx[BN + p]) * inv - x;
    float vy = (party[p] + party[BN + p]) * inv - y;
    float vz = (partz[p] + partz[BN + p]) * inv - z;
    #pragma unroll
    for (int i = 0; i < 8; ++i) {
        int ch = o * 8 + i;
        const float* wm = w_m2 + ch * 16;
        float pos = 0.f;
        #pragma unroll
        for (int c = 0; c < 16; ++c) pos += wm[c] * s_pf16[ptL][c];
        pos = pos * (g_m2[ch] * invs) + b_m2[ch];
        const float* wv = w_v + ch * 6;
        float vv = wv[0] * vx + wv[1] * vy + wv[2] * vz + wv[3] * x + wv[4] * y + wv[5] * z;
        vv = vv * (g_v[ch] * invs) + b_v[ch];
        s_g64[ptL][ch] = gelu_f(vv + pos);
    }
    __syncthreads();

    // phase D: out conv 64->32 + BN; outputs o*4..o*4+3
    #pragma unroll
    for (int i = 0; i < 4; ++i) {
        int ch = o * 4 + i;
        const float* w = w_out + ch * 64;
        float s = 0.f;
        #pragma unroll
        for (int c = 0; c < 64; ++c) s += w[c] * s_g64[ptL][c];
        out[((size_t)b * 32 + ch) * NN + n] = s * (g_out[ch] * invs) + b_out[ch];
    }
}

extern "C" void kernel_launch(void* const* d_in, const int* in_sizes, int n_in,
                              void* d_out, int out_size, void* d_ws, size_t ws_size,
                              hipStream_t stream) {
    const float* xyz  = (const float*)d_in[0];
    const float* w_q  = (const float*)d_in[1];
    const float* g_q  = (const float*)d_in[2];
    const float* b_q  = (const float*)d_in[3];
    const float* w_k  = (const float*)d_in[4];
    const float* g_k  = (const float*)d_in[5];
    const float* b_k  = (const float*)d_in[6];
    const float* w_v  = (const float*)d_in[7];
    const float* g_v  = (const float*)d_in[8];
    const float* b_v  = (const float*)d_in[9];
    const float* w_pe = (const float*)d_in[10];
    const float* b_pe = (const float*)d_in[11];
    const float* g_pe = (const float*)d_in[12];
    const float* bb_pe= (const float*)d_in[13];
    const float* w_m1 = (const float*)d_in[14];
    const float* g_m1 = (const float*)d_in[15];
    const float* b_m1 = (const float*)d_in[16];
    const float* w_m2 = (const float*)d_in[17];
    const float* g_m2 = (const float*)d_in[18];
    const float* b_m2 = (const float*)d_in[19];
    const float* w_out= (const float*)d_in[20];
    const float* g_out= (const float*)d_in[21];
    const float* b_out= (const float*)d_in[22];

    float* ws = (float*)d_ws;
    float*  qv     = ws;                               // BN
    float*  kv     = ws + (size_t)1  * BN;             // BN
    float4* pts4   = (float4*)(ws + (size_t)2  * BN);  // 4BN
    float*  radius = ws + (size_t)6  * BN;             // BN
    float*  Zv     = ws + (size_t)7  * BN;             // BN
    float*  colsum = ws + (size_t)8  * BN;             // BN
    float4* recB   = (float4*)(ws + (size_t)9  * BN);  // 8BN
    float4* recC   = (float4*)(ws + (size_t)17 * BN);  // 8BN
    float4* recD   = (float4*)(ws + (size_t)25 * BN);  // 8BN
    float4* recE   = (float4*)(ws + (size_t)33 * BN);  // 8BN
    int*    idxg   = (int*)   (ws + (size_t)41 * BN);  // 20BN
    float*  part1  = ws + (size_t)61 * BN;             // 2BN
    float*  part3  = ws + (size_t)63 * BN;             // 2BN
    float*  part5  = ws + (size_t)65 * BN;             // 2BN
    float*  part7  = ws + (size_t)67 * BN;             // 2BN
    float*  partx  = ws + (size_t)69 * BN;             // 2BN
    float*  party  = ws + (size_t)71 * BN;             // 2BN
    float*  partz  = ws + (size_t)73 * BN;             // 2BN

    const int PB = (BN / 64) * 2;   // 512 blocks of 1024 threads

    k0_prep<<<BN / 256, 256, 0, stream>>>(xyz, w_q, g_q, b_q, w_k, g_k, b_k, qv, kv, pts4);
    p1_kd<<<PB, 1024, 0, stream>>>(pts4, part1);
    k2_radius<<<BB, 1024, 0, stream>>>(part1, pts4, qv, kv, radius, recB);
    p3_Zk7<<<PB, 1024, 0, stream>>>(recB, pts4, radius, part3, idxg);
    r3_Z<<<BN / 256, 256, 0, stream>>>(part3, pts4, qv, radius, Zv, recC);
    p4_colsum<<<PB, 1024, 0, stream>>>(recC, recB, part5);
    r4_colsum<<<BN / 256, 256, 0, stream>>>(part5, pts4, kv, colsum, recD);
    p5_rs<<<PB, 1024, 0, stream>>>(recD, recB, part7);
    r5_rs<<<BN / 256, 256, 0, stream>>>(part7, Zv, recC, pts4, recE);
    p6_smooth<<<PB, 1024, 0, stream>>>(recE, recB, partx, party, partz);
    k8_final<<<BN / 32, 256, 0, stream>>>(xyz, partx, party, partz, colsum, idxg,
                                          w_v, g_v, b_v,
                                          w_pe, b_pe, g_pe, bb_pe,
                                          w_m1, g_m1, b_m1,
                                          w_m2, g_m2, b_m2,
                                          w_out, g_out, b_out,
                                          (float*)d_out);
}